// Round 9
// baseline (1187.039 us; speedup 1.0000x reference)
//
#include <hip/hip_runtime.h>

#define BB 8
#define TT 2048
#define CC 1024
#define FF 4096
#define MM (BB*TT)   // 16384

typedef unsigned short u16;
typedef __bf16 bf16x8 __attribute__((ext_vector_type(8)));
typedef float f32x4 __attribute__((ext_vector_type(4)));

__device__ __forceinline__ u16 f2bf(float f) {
  unsigned int u = __float_as_uint(f);
  u += 0x7fffu + ((u >> 16) & 1u);     // RNE to bf16
  return (u16)(u >> 16);
}
__device__ __forceinline__ float bf2f(u16 h) {
  unsigned int u = ((unsigned int)h) << 16;
  return __uint_as_float(u);
}
__device__ __forceinline__ float sigm(float x) { return 1.f / (1.f + __expf(-x)); }

__device__ __forceinline__ void async16(const void* g, void* l) {
  __builtin_amdgcn_global_load_lds(
      (const __attribute__((address_space(1))) unsigned int*)g,
      (__attribute__((address_space(3))) unsigned int*)l, 16, 0, 0);
}

// ---------------------------------------------------------------------------
// NT GEMM: C[m,n] = sum_k A[m,k]*W[n,k], A [M,K] bf16 row-major, W [N,K] bf16.
//
// 256x256 tile, BK=64, 512 thr (8 waves 2Mx4N; per wave 128x64 out = 8x4
// frags of 16x16x32 MFMA). FOUR phases/K-tile of 16 MFMA, TWO barriers/tile.
// All DS gates are unconditional lgkmcnt(0) — correctness does not depend
// on counted-gate ordering assumptions (round-6/7 NaN suspect). Reads are
// issued at PHASE END (after the MFMA burst):
//   - at F1->F2 and F2->F3 the barrier wait absorbs the read latency
//   - at F3->F0 the 16-glds stage issue absorbs most of it
//   - only F0->F1 exposes ~one read latency per tile
// Phase p: { LGKM(0); SCHED0; EXEC16 ; reads-for-next ; [stages/vmcnt/bar] }
//   F0: EXEC a0xb01 ; read a1(t)
//   F1: EXEC a1xb01 ; read b23(t) ; vmcnt(0)+BARRIER   (publishes stages)
//   F2: EXEC a0xb23 ; read b01(t+1) ; BARRIER          (releases buf beta)
//   F3: EXEC a1xb23 ; read a0(t+1) ; stage tile t+2 -> buf beta (16 glds)
// Liveness (verified): all buf-beta reads (a1@F0,b23@F1 drained by next
// phase's LGKM(0); a0/b01 of tile t read in F3/F2 of t-1, drained by
// F0(t)/F3(t-1) LGKM(0)) complete before the end-F2 barrier -> F3 staging
// safe. Staged tile t+2 first read at end-F2(t+1), strictly after the
// vmcnt(0)+BARRIER at end-F1(t+1). Tail needs no special vmcnt.
// Banks: a0/a1[4][2] + b01/b23[2][2] = 96 frag regs + 128 acc -> no spill
// (round-3 lesson). B LDS layout permuted [half][band][32rows]; chunk^row&7
// source-side XOR swizzle (conflict-free, SQ_LDS_BANK_CONFLICT=0 r1-r5).
// MODE 0: Cf[idx] = v (f32).      MODE 2: Cb[idx] = bf16(relu(v)^2).
// MODE 3: Cb[idx] = bf16(v).      MODE 4: Cf[idx] += sigm(R[idx]) * v.
// ---------------------------------------------------------------------------
#define GROUP_M 16

#define DSRD(d, a, o) \
  asm volatile("ds_read_b128 %0, %1 offset:%c2" : "=v"(d) : "v"(a), "i"(o))

#define MFMA16(A_, B_, C_) \
  (C_) = __builtin_amdgcn_mfma_f32_16x16x32_bf16( \
      __builtin_bit_cast(bf16x8, (A_)), __builtin_bit_cast(bf16x8, (B_)), (C_), 0, 0, 0)

#define SCHED0  __builtin_amdgcn_sched_barrier(0)
#define BARRIER __builtin_amdgcn_s_barrier()
#define LGKM0   asm volatile("s_waitcnt lgkmcnt(0)")

// 8 ds_read_b128 into bank[mi][kh]: A rows (MH*4+mi)*16, kh=0,1
#define READ_A8(bank, BETA, MH) do { \
  DSRD(bank[0][0], aAddr0, (BETA)*32768 + ((MH)*4+0)*2048); \
  DSRD(bank[0][1], aAddr1, (BETA)*32768 + ((MH)*4+0)*2048); \
  DSRD(bank[1][0], aAddr0, (BETA)*32768 + ((MH)*4+1)*2048); \
  DSRD(bank[1][1], aAddr1, (BETA)*32768 + ((MH)*4+1)*2048); \
  DSRD(bank[2][0], aAddr0, (BETA)*32768 + ((MH)*4+2)*2048); \
  DSRD(bank[2][1], aAddr1, (BETA)*32768 + ((MH)*4+2)*2048); \
  DSRD(bank[3][0], aAddr0, (BETA)*32768 + ((MH)*4+3)*2048); \
  DSRD(bank[3][1], aAddr1, (BETA)*32768 + ((MH)*4+3)*2048); \
} while (0)

// 4 ds_read_b128 into bank[ni][kh]: B permuted rho = NP*128 + wni*32 + ni*16 + lm
#define READ_B4(bank, BETA, NP) do { \
  DSRD(bank[0][0], bAddr0, (BETA)*32768 + (NP)*16384 + 0*2048); \
  DSRD(bank[0][1], bAddr1, (BETA)*32768 + (NP)*16384 + 0*2048); \
  DSRD(bank[1][0], bAddr0, (BETA)*32768 + (NP)*16384 + 1*2048); \
  DSRD(bank[1][1], bAddr1, (BETA)*32768 + (NP)*16384 + 1*2048); \
} while (0)

// 16 MFMA: kh0 sweep (8 independent) then kh1 sweep (dep distance 8)
#define EXEC16(ABANK, BBANK, AO, NO) do { \
  __builtin_amdgcn_s_setprio(1); \
  _Pragma("unroll") \
  for (int mi = 0; mi < 4; ++mi) \
    _Pragma("unroll") \
    for (int ni = 0; ni < 2; ++ni) \
      MFMA16(ABANK[mi][0], BBANK[ni][0], acc[(AO)+mi][(NO)+ni]); \
  _Pragma("unroll") \
  for (int mi = 0; mi < 4; ++mi) \
    _Pragma("unroll") \
    for (int ni = 0; ni < 2; ++ni) \
      MFMA16(ABANK[mi][1], BBANK[ni][1], acc[(AO)+mi][(NO)+ni]); \
  __builtin_amdgcn_s_setprio(0); SCHED0; } while (0)

// one K-tile = 4 phases, 2 barriers, lgkmcnt(0)-only gates.
#define TILE(BETA, T2A, ST, RD) do { \
  /* F0: EXEC a0 x b01 ; read a1(t) */ \
  LGKM0; SCHED0; EXEC16(a0, b01, 0, 0); \
  READ_A8(a1, BETA, 1); \
  /* F1: EXEC a1 x b01 ; read b23(t) ; publish stages */ \
  LGKM0; SCHED0; EXEC16(a1, b01, 4, 0); \
  READ_B4(b23, BETA, 1); \
  asm volatile("s_waitcnt vmcnt(0)"); \
  BARRIER; SCHED0; \
  /* F2: EXEC a0 x b23 ; read b01(t+1) ; barrier releases buf beta */ \
  LGKM0; SCHED0; EXEC16(a0, b23, 0, 2); \
  if (RD) READ_B4(b01, (BETA)^1, 0); \
  BARRIER; SCHED0; \
  /* F3: EXEC a1 x b23 ; read a0(t+1) ; stage tile t+2 into buf beta */ \
  LGKM0; SCHED0; EXEC16(a1, b23, 4, 2); \
  if (RD) READ_A8(a0, (BETA)^1, 0); \
  if (ST) { stA(BETA, 0, T2A); stA(BETA, 1, T2A); \
            stA(BETA, 2, T2A); stA(BETA, 3, T2A); \
            stB(BETA, 0, T2A); stB(BETA, 1, T2A); \
            stB(BETA, 2, T2A); stB(BETA, 3, T2A); } \
} while (0)

template<int MODE>
__global__ __launch_bounds__(512, 2) void gemm_bt(
    const u16* __restrict__ A, const u16* __restrict__ W,
    float* __restrict__ Cf, u16* __restrict__ Cb,
    const u16* __restrict__ R, int N, int K)
{
  __shared__ __align__(16) u16 ldsA[2][256 * 64];   // 64 KB
  __shared__ __align__(16) u16 ldsB[2][256 * 64];   // 64 KB (permuted layout)

  const int tid  = threadIdx.x;
  const int wave = tid >> 6;
  const int lane = tid & 63;
  const int wmi  = wave >> 2;          // 0..1 : wave M row (128 rows each)
  const int wni  = wave & 3;           // 0..3 : wave N col (64 cols each)
  const int lm   = lane & 15;
  const int lq   = lane >> 4;

  // tile swizzle (grid.x = M/256, divisible by GROUP_M; grid.y = N-tiles)
  const int bid  = blockIdx.x + blockIdx.y * gridDim.x;
  const int gsz  = GROUP_M * gridDim.y;
  const int gid  = bid / gsz;
  const int rem  = bid - gid * gsz;
  const int bm   = (gid * GROUP_M + (rem % GROUP_M)) * 256;
  const int bn   = (rem / GROUP_M) * 256;

  const int NT = K >> 6;               // K-tiles of 64 (NT even, >= 4)

  // staging: round q = 64 LDS rows; wave w writes rows q*64+w*8 .. +8.
  // source chunk pre-swizzle: LDS chunk (lane&7) <- global chunk (lane&7)^(lane>>3)
  const int ls     = lane >> 3;
  const int schunk = (lane & 7) ^ ls;
  const int rowA   = wave * 8 + ls;                              // A: rho == global row
  const int rowB   = (wave >> 2) * 64 + (wave & 3) * 8 + ls;     // B: base of permuted map
  const u16* gA = A + (size_t)(bm + rowA) * K + schunk * 8;
  const u16* gB = W + (size_t)(bn + rowB) * K + schunk * 8;
  const size_t rowK = (size_t)64 * K;

  auto stA = [&](int buf, int q, int t2) {
    async16(gA + (size_t)t2 * 64 + (size_t)q * rowK,
            &ldsA[buf][(q * 64 + wave * 8) * 64]);
  };
  // B permuted: LDS rho = half*128 + band*32 + r ; global row = band*64+half*32+r
  // => per-q global row delta from rowB: {0,128,32,160}
  auto stB = [&](int buf, int q, int t2) {
    const int qrow = (q == 0) ? 0 : (q == 1) ? 128 : (q == 2) ? 32 : 160;
    async16(gB + (size_t)t2 * 64 + (size_t)qrow * K,
            &ldsB[buf][(q * 64 + wave * 8) * 64]);
  };

  const unsigned lAbase =
      (unsigned)(size_t)(const __attribute__((address_space(3))) u16*)&ldsA[0][0];
  const unsigned lBbase =
      (unsigned)(size_t)(const __attribute__((address_space(3))) u16*)&ldsB[0][0];
  // A frag: row = wmi*128 + mi*16 + lm, byte = row*128 + ((lq+4kh)^(lm&7))*16
  const unsigned aAddr0 = lAbase + (unsigned)((wmi * 128 + lm) * 128 + (((lq    ) ^ (lm & 7)) * 16));
  const unsigned aAddr1 = lAbase + (unsigned)((wmi * 128 + lm) * 128 + (((lq + 4) ^ (lm & 7)) * 16));
  // B frag: rho = np*128 + wni*32 + ni*16 + lm  (np,ni via offset imm)
  const unsigned bAddr0 = lBbase + (unsigned)((wni * 32 + lm) * 128 + (((lq    ) ^ (lm & 7)) * 16));
  const unsigned bAddr1 = lBbase + (unsigned)((wni * 32 + lm) * 128 + (((lq + 4) ^ (lm & 7)) * 16));

  f32x4 acc[8][4] = {};
  f32x4 a0[4][2], a1[4][2], b01[2][2], b23[2][2];   // 96 frag regs

  // ---------------- prologue: stage tiles 0,1; preload a0(0), b01(0)
  stA(0, 0, 0); stA(0, 1, 0); stA(0, 2, 0); stA(0, 3, 0);
  stB(0, 0, 0); stB(0, 1, 0); stB(0, 2, 0); stB(0, 3, 0);
  stA(1, 0, 1); stA(1, 1, 1); stA(1, 2, 1); stA(1, 3, 1);
  stB(1, 0, 1); stB(1, 1, 1); stB(1, 2, 1); stB(1, 3, 1);
  asm volatile("s_waitcnt vmcnt(0)");
  BARRIER;
  READ_B4(b01, 0, 0);       // "end-F2(-1)" read
  READ_A8(a0, 0, 0);        // "end-F3(-1)" read
  SCHED0;                   // F0's LGKM0 drains these before first EXEC

  // ---------------- main loop: tiles 0 .. NT-3 staged+full (2 per iter)
  for (int t = 0; t + 3 < NT; t += 2) {
    TILE(0, t + 2, 1, 1);
    TILE(1, t + 3, 1, 1);
  }

  // ---------------- tail: tiles NT-2, NT-1
  TILE(0, 0, 0, 1);
  TILE(1, 0, 0, 0);

  // epilogue. C/D layout (verified m89/m91): col = lane&15, row = (lane>>4)*4 + reg
  const int row0 = bm + wmi * 128 + lq * 4;
  const int col0 = bn + wni * 64 + lm;
#pragma unroll
  for (int mi = 0; mi < 8; ++mi)
#pragma unroll
    for (int ni = 0; ni < 4; ++ni) {
      size_t base = (size_t)(row0 + mi * 16) * N + (col0 + ni * 16);
#pragma unroll
      for (int r2 = 0; r2 < 4; ++r2) {
        size_t idx = base + (size_t)r2 * N;
        float v = acc[mi][ni][r2];
        if (MODE == 0) Cf[idx] = v;
        if (MODE == 2) { float rl = v > 0.f ? v : 0.f; Cb[idx] = f2bf(rl * rl); }
        if (MODE == 3) Cb[idx] = f2bf(v);
        if (MODE == 4) Cf[idx] += sigm(bf2f(R[idx])) * v;
      }
    }
}

// ---------------------------------------------------------------------------
// LayerNorm both rows t and t-1, time-shift mix, bf16 cast.
// One block per row (b,t). ov/oxb may be null (phase-2 use).
// oxb (raw x cast) is written at pitch 2*CC (the A' interleaved buffer).
// ---------------------------------------------------------------------------
__global__ __launch_bounds__(256) void prep_mix(
    const float* __restrict__ x,
    const float* __restrict__ lnw, const float* __restrict__ lnb,
    const float* __restrict__ mk, const float* __restrict__ mv, const float* __restrict__ mr,
    u16* __restrict__ ok, u16* __restrict__ ov, u16* __restrict__ orr,
    u16* __restrict__ oxb)
{
  const int m = blockIdx.x;
  const int t = m & (TT - 1);
  const int tid = threadIdx.x;
  const int wave = tid >> 6, lane = tid & 63;
  const bool hasp = (t != 0);

  const float4 xc4 = ((const float4*)(x + (size_t)m * CC))[tid];
  float4 xp4 = make_float4(0.f, 0.f, 0.f, 0.f);
  if (hasp) xp4 = ((const float4*)(x + (size_t)(m - 1) * CC))[tid];

  float s0 = xc4.x + xc4.y + xc4.z + xc4.w;
  float s1 = xc4.x*xc4.x + xc4.y*xc4.y + xc4.z*xc4.z + xc4.w*xc4.w;
  float s2 = xp4.x + xp4.y + xp4.z + xp4.w;
  float s3 = xp4.x*xp4.x + xp4.y*xp4.y + xp4.z*xp4.z + xp4.w*xp4.w;
#pragma unroll
  for (int off2 = 32; off2 > 0; off2 >>= 1) {
    s0 += __shfl_xor(s0, off2);
    s1 += __shfl_xor(s1, off2);
    s2 += __shfl_xor(s2, off2);
    s3 += __shfl_xor(s3, off2);
  }
  __shared__ float red[4][4];
  if (lane == 0) { red[0][wave] = s0; red[1][wave] = s1; red[2][wave] = s2; red[3][wave] = s3; }
  __syncthreads();
  const float S0 = red[0][0] + red[0][1] + red[0][2] + red[0][3];
  const float S1 = red[1][0] + red[1][1] + red[1][2] + red[1][3];
  const float S2 = red[2][0] + red[2][1] + red[2][2] + red[2][3];
  const float S3 = red[3][0] + red[3][1] + red[3][2] + red[3][3];
  const float inv = 1.f / (float)CC;
  const float muc = S0 * inv, varc = S1 * inv - muc * muc, rsc = rsqrtf(varc + 1e-5f);
  const float mup = S2 * inv, varp = S3 * inv - mup * mup, rsp = rsqrtf(varp + 1e-5f);

  const float xc[4] = {xc4.x, xc4.y, xc4.z, xc4.w};
  const float xp[4] = {xp4.x, xp4.y, xp4.z, xp4.w};
  const float4 lw4 = ((const float4*)lnw)[tid];
  const float4 lb4 = ((const float4*)lnb)[tid];
  const float lw[4] = {lw4.x, lw4.y, lw4.z, lw4.w};
  const float lb[4] = {lb4.x, lb4.y, lb4.z, lb4.w};
  const float4 mk4 = ((const float4*)mk)[tid];
  const float mka[4] = {mk4.x, mk4.y, mk4.z, mk4.w};
  const float4 mr4 = ((const float4*)mr)[tid];
  const float mra[4] = {mr4.x, mr4.y, mr4.z, mr4.w};
  float mva[4] = {0.f, 0.f, 0.f, 0.f};
  if (ov) {
    const float4 mv4 = ((const float4*)mv)[tid];
    mva[0] = mv4.x; mva[1] = mv4.y; mva[2] = mv4.z; mva[3] = mv4.w;
  }

  ushort4 wk2, wv2, wr2, wb2;
  u16* pk = (u16*)&wk2; u16* pv = (u16*)&wv2; u16* pr = (u16*)&wr2; u16* pb = (u16*)&wb2;
#pragma unroll
  for (int j = 0; j < 4; ++j) {
    float h  = (xc[j] - muc) * rsc * lw[j] + lb[j];
    float hh = hasp ? (xp[j] - mup) * rsp * lw[j] + lb[j] : 0.f;
    pk[j] = f2bf(h * mka[j] + hh * (1.f - mka[j]));
    pv[j] = f2bf(h * mva[j] + hh * (1.f - mva[j]));
    pr[j] = f2bf(h * mra[j] + hh * (1.f - mra[j]));
    pb[j] = f2bf(xc[j]);
  }
  ((ushort4*)(ok + (size_t)m * CC))[tid] = wk2;
  if (ov)  ((ushort4*)(ov  + (size_t)m * CC))[tid] = wv2;
  ((ushort4*)(orr + (size_t)m * CC))[tid] = wr2;
  if (oxb) ((ushort4*)(oxb + (size_t)m * (2 * CC)))[tid] = wb2;   // A' xb half
}

// ---------------------------------------------------------------------------
// WKV blocked 3-phase parallel scan. Output goes to the rwkv half of the
// interleaved A' buffer: out pitch = 2*CC.
// ---------------------------------------------------------------------------
#define WKV_CPB 32
#define WKV_NCH 32
#define WKV_L   (TT / WKV_NCH)   // 64

__global__ __launch_bounds__(1024) void wkv_scan(
    const u16* __restrict__ k, const u16* __restrict__ v, const u16* __restrict__ r,
    const float* __restrict__ decay, const float* __restrict__ first,
    u16* __restrict__ out)   // points at A' + CC (rwkv half), pitch 2*CC
{
  const int b  = blockIdx.x >> 5;
  const int c0 = (blockIdx.x & 31) * WKV_CPB;
  const int tid = threadIdx.x;
  const int cl = tid & 31;
  const int j  = tid >> 5;
  const int c  = c0 + cl;

  const float w   = -__expf(decay[c]);
  const float lam = __expf(w);
  const float eu  = __expf(first[c]);

  const size_t base  = (size_t)b * TT * CC + (size_t)j * WKV_L * CC + c;
  size_t obase = ((size_t)b * TT + (size_t)j * WKV_L) * (2 * CC) + c;

  // phase 1: local scan (state only)
  float a = 0.f, bb = 0.f;
  size_t idx = base;
  for (int i = 0; i < WKV_L; ++i, idx += CC) {
    const float kt = bf2f(k[idx]), vt = bf2f(v[idx]);
    const float ek = __expf(kt);
    a  = fmaf(lam, a, ek * vt);
    bb = fmaf(lam, bb, ek);
  }

  // phase 2: exclusive carry scan over chunks
  __shared__ float sA[WKV_NCH][WKV_CPB];
  __shared__ float sB[WKV_NCH][WKV_CPB];
  sA[j][cl] = a; sB[j][cl] = bb;
  __syncthreads();
  if (tid < WKV_CPB) {
    float ca = 0.f, cb = 0.f;
    const float cw   = -__expf(decay[c0 + tid]);
    const float cLam = __expf(cw * (float)WKV_L);
#pragma unroll
    for (int q = 0; q < WKV_NCH; ++q) {
      const float ta = sA[q][tid], tb = sB[q][tid];
      sA[q][tid] = ca; sB[q][tid] = cb;
      ca = fmaf(cLam, ca, ta);
      cb = fmaf(cLam, cb, tb);
    }
  }
  __syncthreads();
  a = sA[j][cl]; bb = sB[j][cl];

  // phase 3: replay with carry-in, emit sigmoid(r)*y into A' rwkv half
  idx = base;
  for (int i = 0; i < WKV_L; ++i, idx += CC, obase += 2 * CC) {
    const float kt = bf2f(k[idx]), vt = bf2f(v[idx]), rt = bf2f(r[idx]);
    const float ek = __expf(kt);
    const float e2 = eu * ek;
    const float y  = (a + e2 * vt) / (bb + e2);
    out[obase] = f2bf(sigm(rt) * y);
    a  = fmaf(lam, a, ek * vt);
    bb = fmaf(lam, bb, ek);
  }
}

// ---------------------------------------------------------------------------
// Weight f32 -> bf16 conversion. Segments 3 (Wo) and 4 (Wsh) are interleaved
// into W' = [Wsh | Wo] rows of pitch 2048 for the merged short+Wo GEMM.
// ---------------------------------------------------------------------------
struct ConvArgs { const float* src[8]; int end[8]; int dstoff[8]; };

__global__ __launch_bounds__(256) void conv_w(ConvArgs args, u16* __restrict__ dst)
{
  const int i = (blockIdx.x * 256 + threadIdx.x) * 4;
  int seg = 0;
  const float* sp = args.src[0];
  int base = 0;
#pragma unroll
  for (int s = 1; s < 8; ++s) {
    if (i >= args.end[s - 1]) { seg = s; sp = args.src[s]; base = args.end[s - 1]; }
  }
  const int l = i - base;
  const float4 vv = *(const float4*)(sp + l);
  int dsti;
  if (seg == 3)      { int row = l >> 10, col = l & 1023; dsti = args.dstoff[3] + row * 2048 + 1024 + col; }
  else if (seg == 4) { int row = l >> 10, col = l & 1023; dsti = args.dstoff[4] + row * 2048 + col; }
  else               dsti = args.dstoff[seg] + l;
  ushort4 d;
  d.x = f2bf(vv.x); d.y = f2bf(vv.y); d.z = f2bf(vv.z); d.w = f2bf(vv.w);
  *(ushort4*)(dst + dsti) = d;
}

extern "C" void kernel_launch(void* const* d_in, const int* in_sizes, int n_in,
                              void* d_out, int out_size, void* d_ws, size_t ws_size,
                              hipStream_t stream)
{
  const float* x    = (const float*)d_in[0];
  const float* ln1w = (const float*)d_in[1];
  const float* ln1b = (const float*)d_in[2];
  const float* ln2w = (const float*)d_in[3];
  const float* ln2b = (const float*)d_in[4];
  const float* tdec = (const float*)d_in[5];
  const float* tfir = (const float*)d_in[6];
  const float* amk  = (const float*)d_in[7];
  const float* amv  = (const float*)d_in[8];
  const float* amr  = (const float*)d_in[9];
  const float* Wk   = (const float*)d_in[10];
  const float* Wv   = (const float*)d_in[11];
  const float* Wr   = (const float*)d_in[12];
  const float* Wo   = (const float*)d_in[13];
  const float* fmk  = (const float*)d_in[14];
  const float* fmr  = (const float*)d_in[15];
  const float* WfK  = (const float*)d_in[16];
  const float* WfR  = (const float*)d_in[17];
  const float* WfV  = (const float*)d_in[18];
  const float* Wsh  = (const float*)d_in[19];
  float* out = (float*)d_out;
  char* ws = (char*)d_ws;

  // workspace: 28 MB bf16 weights + six 32 MB regions = 230,686,720 B total.
  u16* wW = (u16*)(ws);
  u16* U0 = (u16*)(ws + 29360128);
  u16* U1 = (u16*)(ws + 62914560);
  u16* U2 = (u16*)(ws + 96468992);
  u16* U3 = (u16*)(ws + 130023424);
  u16* U4 = (u16*)(ws + 163577856);   // A' = U4+U5, 64 MB contiguous

  // liveness-based aliases:
  u16* xk   = U0;          // prep1
  u16* xv   = U1;
  u16* xr   = U2;
  u16* Ap   = U4;          // A' [M, 2C]: cols 0..C-1 = bf16(x), C..2C-1 = rwkv
  u16* kbuf = U3;          // k = xk*Wk   (U0 dead after)
  u16* vbuf = U0;          // v = xv*Wv   (U1 dead after)
  u16* rbuf = U1;          // r = xr*Wr   (U2 dead after)
  u16* gk   = U0;          // prep2       (U0 dead after wkv)
  u16* gr   = U1;
  u16* kkb  = U2;          // kk [M,F] bf16 = 128 MB, spans U2..U5 (all dead)
  u16* rffn = U0;          // r_ffn       (gk/U0 dead after kk GEMM)

  u16* bWk   = wW + 0;
  u16* bWv   = wW + 1048576;
  u16* bWr   = wW + 2097152;
  u16* bWsWo = wW + 3145728;   // W' [C, 2C] interleaved [Wsh | Wo]
  u16* bWfR  = wW + 5242880;
  u16* bWfK  = wW + 6291456;
  u16* bWfV  = wW + 10485760;

  ConvArgs ca;
  ca.src[0] = Wk;  ca.src[1] = Wv;  ca.src[2] = Wr;  ca.src[3] = Wo;
  ca.src[4] = Wsh; ca.src[5] = WfR; ca.src[6] = WfK; ca.src[7] = WfV;
  const int e = 1048576;
  ca.end[0] = e;     ca.end[1] = 2*e;  ca.end[2] = 3*e;  ca.end[3] = 4*e;
  ca.end[4] = 5*e;   ca.end[5] = 6*e;  ca.end[6] = 10*e; ca.end[7] = 14*e;
  ca.dstoff[0] = 0;     ca.dstoff[1] = e;    ca.dstoff[2] = 2*e;
  ca.dstoff[3] = 3*e;   ca.dstoff[4] = 3*e;  // both into W' (interleaved)
  ca.dstoff[5] = 5*e;   ca.dstoff[6] = 6*e;  ca.dstoff[7] = 10*e;

  conv_w<<<14336, 256, 0, stream>>>(ca, wW);
  prep_mix<<<MM, 256, 0, stream>>>(x, ln1w, ln1b, amk, amv, amr, xk, xv, xr, Ap);

  dim3 g8(MM / 256, CC / 256);
  gemm_bt<3><<<g8, 512, 0, stream>>>(xk, bWk, nullptr, kbuf, nullptr, CC, CC);
  gemm_bt<3><<<g8, 512, 0, stream>>>(xv, bWv, nullptr, vbuf, nullptr, CC, CC);
  gemm_bt<3><<<g8, 512, 0, stream>>>(xr, bWr, nullptr, rbuf, nullptr, CC, CC);

  wkv_scan<<<BB * (CC / WKV_CPB), 1024, 0, stream>>>(kbuf, vbuf, rbuf, tdec, tfir, Ap + CC);

  // out = [xb | rwkv] * [Wsh | Wo]^T   (single K=2048 GEMM)
  gemm_bt<0><<<g8, 512, 0, stream>>>(Ap, bWsWo, out, nullptr, nullptr, CC, 2 * CC);

  prep_mix<<<MM, 256, 0, stream>>>(out, ln2w, ln2b, fmk, nullptr, fmr, gk, nullptr, gr, nullptr);

  dim3 gF(MM / 256, FF / 256);
  gemm_bt<2><<<gF, 512, 0, stream>>>(gk, bWfK, nullptr, kkb, nullptr, FF, CC);  // kk = relu(gk*WfK)^2
  gemm_bt<3><<<g8, 512, 0, stream>>>(gr, bWfR, nullptr, rffn, nullptr, CC, CC);
  // out += sigm(rffn) * (kk * WfV)   (fused final_add)
  gemm_bt<4><<<g8, 512, 0, stream>>>(kkb, bWfV, out, nullptr, rffn, CC, FF);
}